// Round 4
// baseline (607.165 us; speedup 1.0000x reference)
//
#include <hip/hip_runtime.h>

#define TDIM 256
#define THEADS 8
#define TB 32
#define TN 8192
#define BLK_PER_B 32
#define WAVES_PB 4
#define WV_PER_B (BLK_PER_B*WAVES_PB)   // 128 waves per batch
#define ITERS (TN/WV_PER_B)             // 64 tokens per wave
#define ACC_PER_B 2312                  // Y 8*256 + E 8 + S 256
#define PPAD 2368                       // padded partial stride (floats)

#if __has_builtin(__builtin_amdgcn_exp2f)
#define EXP2(x) __builtin_amdgcn_exp2f(x)
#else
#define EXP2(x) exp2f(x)
#endif

// butterfly stage via DPP (pure VALU, no DS pipe)
template<int CTRL>
__device__ __forceinline__ float dppadd(float v) {
  int t = __builtin_amdgcn_update_dpp(0, __float_as_int(v), CTRL, 0xF, 0xF, true);
  return v + __int_as_float(t);
}
// xor16 within each 32-lane group via ds_swizzle bit-mode
__device__ __forceinline__ float swzadd16(float v) {
  int t = __builtin_amdgcn_ds_swizzle(__float_as_int(v), 0x401F); // (16<<10)|0x1F
  return v + __int_as_float(t);
}
// full 64-lane sum, result on every lane
__device__ __forceinline__ float red64(float v) {
  v = dppadd<0xB1>(v);   // quad_perm [1,0,3,2] = xor1
  v = dppadd<0x4E>(v);   // quad_perm [2,3,0,1] = xor2
  v = dppadd<0x141>(v);  // row_half_mirror     = xor7 (~xor4 after 1,2)
  v = dppadd<0x128>(v);  // row_ror:8           = xor8 (within 16)
  v = swzadd16(v);       // xor16 (within 32)
  return v + __shfl_xor(v, 32, 64);  // xor32
}

// prep: q = ct@Wq+bq ; w1[b,g,c] = log2e/sqrt(32) * sum_h Wt1[h,g] * (Wkv_k[c,32h+d]·q[b,32h+d])
__global__ void tmca_prep(const float* __restrict__ ct, const float* __restrict__ Wq,
                          const float* __restrict__ bq, const float* __restrict__ Wkv,
                          const float* __restrict__ Wt1, float* __restrict__ w1) {
  int b = blockIdx.x, t = threadIdx.x;
  __shared__ float sct[TDIM], sq[TDIM], st1[64];
  sct[t] = ct[b * TDIM + t];
  if (t < 64) st1[t] = Wt1[t];
  __syncthreads();
  float a = bq[t];
  for (int c = 0; c < TDIM; ++c) a = fmaf(sct[c], Wq[c * TDIM + t], a);
  sq[t] = a;
  __syncthreads();
  float ph[THEADS];
  #pragma unroll
  for (int h = 0; h < THEADS; ++h) {
    float s = 0.f;
    #pragma unroll 8
    for (int d = 0; d < 32; ++d) s = fmaf(Wkv[t * 512 + h * 32 + d], sq[h * 32 + d], s);
    ph[h] = s;
  }
  const float sc = 0.17677669529663687f * 1.4426950408889634f;  // 1/sqrt(32) * log2(e)
  #pragma unroll
  for (int g = 0; g < THEADS; ++g) {
    float s = 0.f;
    #pragma unroll
    for (int h = 0; h < THEADS; ++h) s = fmaf(ph[h], st1[h * THEADS + g], s);
    w1[(b * THEADS + g) * TDIM + t] = s * sc;
  }
}

// streaming pass, one token per wave per iter:
// per (b,g): E = sum_n m*2^s2', Y[c] = sum_n m*2^s2'*X[n,c], S[c] = sum_n X[n,c]
__global__ __launch_bounds__(256, 4) void tmca_main(
    const float* __restrict__ X, const int* __restrict__ mask,
    const float* __restrict__ w1, float* __restrict__ partial) {
  const int b = blockIdx.y, bk = blockIdx.x, tid = threadIdx.x;
  const int wv = tid >> 6, j = tid & 63;
  const int nb = __builtin_amdgcn_readfirstlane(bk * WAVES_PB + wv);  // scalar token base

  const float4* w1b = (const float4*)(w1 + (size_t)b * THEADS * TDIM);
  float4 wg[8];
  #pragma unroll
  for (int g = 0; g < 8; ++g) wg[g] = w1b[g * 64 + j];  // lane j owns ch 4j..4j+3

  float4 Y[8];
  float E[8];
  float4 S = make_float4(0, 0, 0, 0);
  #pragma unroll
  for (int g = 0; g < 8; ++g) { Y[g] = make_float4(0, 0, 0, 0); E[g] = 0.f; }

  // token for iter s: n = nb + s*128 ; float4 addr = base + n*64 + j
  const float4* Xq = (const float4*)(X + (size_t)b * TN * TDIM) + (size_t)nb * 64 + j;
  const int* mb = mask + b * TN + nb;   // scalar base; mb[s*128] is wave-uniform

  auto body = [&](float4 x, float fm) {
    float pg[8];
    #pragma unroll
    for (int g = 0; g < 8; ++g)
      pg[g] = x.x * wg[g].x + x.y * wg[g].y + x.z * wg[g].z + x.w * wg[g].w;
    #pragma unroll
    for (int g = 0; g < 8; ++g) pg[g] = red64(pg[g]);
    #pragma unroll
    for (int g = 0; g < 8; ++g) {
      float e = EXP2(pg[g]) * fm;
      E[g] += e;
      Y[g].x = fmaf(e, x.x, Y[g].x);
      Y[g].y = fmaf(e, x.y, Y[g].y);
      Y[g].z = fmaf(e, x.z, Y[g].z);
      Y[g].w = fmaf(e, x.w, Y[g].w);
    }
    S.x += x.x; S.y += x.y; S.z += x.z; S.w += x.w;
  };

  // 4-deep prefetch ring with compile-time slot indices
  float4 PA = Xq[0uL * 8192], PB = Xq[1uL * 8192], PC = Xq[2uL * 8192], PD = Xq[3uL * 8192];
  int mA = mb[0 * 128], mB = mb[1 * 128], mC = mb[2 * 128], mD = mb[3 * 128];

  for (int it = 0; it < ITERS; it += 4) {
    const bool pf = (it + 4 < ITERS);   // wave-uniform
    {
      float4 x = PA; float fm = (float)mA;
      if (pf) { PA = Xq[(size_t)(it + 4) * 8192]; mA = mb[(it + 4) * 128]; }
      body(x, fm);
    }
    {
      float4 x = PB; float fm = (float)mB;
      if (pf) { PB = Xq[(size_t)(it + 5) * 8192]; mB = mb[(it + 5) * 128]; }
      body(x, fm);
    }
    {
      float4 x = PC; float fm = (float)mC;
      if (pf) { PC = Xq[(size_t)(it + 6) * 8192]; mC = mb[(it + 6) * 128]; }
      body(x, fm);
    }
    {
      float4 x = PD; float fm = (float)mD;
      if (pf) { PD = Xq[(size_t)(it + 7) * 8192]; mD = mb[(it + 7) * 128]; }
      body(x, fm);
    }
  }

  // wave values are complete (full-wave reduce already done for E; Y,S are lane-local ch sums)
  __shared__ float red[WAVES_PB][ACC_PER_B];
  float* sl = red[wv];
  #pragma unroll
  for (int g = 0; g < 8; ++g) ((float4*)(sl + g * TDIM))[j] = Y[g];
  ((float4*)(sl + 2056))[j] = S;
  if (j == 0) {
    #pragma unroll
    for (int g = 0; g < 8; ++g) sl[2048 + g] = E[g];
  }
  __syncthreads();
  float* pb = partial + (size_t)(b * BLK_PER_B + bk) * PPAD;
  for (int idx = tid; idx < ACC_PER_B; idx += 256)
    pb[idx] = red[0][idx] + red[1][idx] + red[2][idx] + red[3][idx];
}

// finalize: reduce partials, z = Wt2^T·(Y/E) + bt2*S, out_pre = z·Wkv_v + T*bkv_v, out = out_pre@Wout+bout
__global__ void tmca_fin(const float* __restrict__ partial, const float* __restrict__ Wkv,
                         const float* __restrict__ bkv, const float* __restrict__ Wt2,
                         const float* __restrict__ bt2, const float* __restrict__ Wout,
                         const float* __restrict__ bout, float* __restrict__ out) {
  int b = blockIdx.x, t = threadIdx.x;
  __shared__ float sacc[ACC_PER_B];
  __shared__ float z[THEADS][TDIM];
  __shared__ float opre[TDIM];
  __shared__ float sWt2[64], sbt2[8];
  const float* pb = partial + (size_t)b * BLK_PER_B * PPAD;
  for (int idx = t; idx < ACC_PER_B; idx += 256) {
    float s = 0.f;
    #pragma unroll 8
    for (int k = 0; k < BLK_PER_B; ++k) s += pb[(size_t)k * PPAD + idx];
    sacc[idx] = s;
  }
  if (t < 64) sWt2[t] = Wt2[t];
  if (t < 8) sbt2[t] = bt2[t];
  __syncthreads();
  float Yc[THEADS];
  #pragma unroll
  for (int g = 0; g < THEADS; ++g) Yc[g] = sacc[g * TDIM + t] / sacc[2048 + g];
  float Sc = sacc[2056 + t];
  #pragma unroll
  for (int g2 = 0; g2 < THEADS; ++g2) {
    float a = 0.f;
    #pragma unroll
    for (int g = 0; g < THEADS; ++g) a = fmaf(sWt2[g * THEADS + g2], Yc[g], a);
    z[g2][t] = a + sbt2[g2] * Sc;
  }
  __syncthreads();
  {
    int g2 = t >> 5;
    float T = 0.f;
    #pragma unroll
    for (int g = 0; g < THEADS; ++g) T += sWt2[g * THEADS + g2];
    T += (float)TN * sbt2[g2];
    float a = 0.f;
    for (int c = 0; c < TDIM; ++c) a = fmaf(z[g2][c], Wkv[c * 512 + 256 + t], a);
    opre[t] = a + T * bkv[256 + t];
  }
  __syncthreads();
  float a = bout[t];
  for (int c = 0; c < TDIM; ++c) a = fmaf(opre[c], Wout[c * TDIM + t], a);
  out[b * TDIM + t] = a;
}

extern "C" void kernel_launch(void* const* d_in, const int* in_sizes, int n_in,
                              void* d_out, int out_size, void* d_ws, size_t ws_size,
                              hipStream_t stream) {
  const float* X    = (const float*)d_in[0];
  const float* ct   = (const float*)d_in[1];
  const int*   msk  = (const int*)d_in[2];
  const float* Wkv  = (const float*)d_in[3];
  const float* bkv  = (const float*)d_in[4];
  const float* Wq   = (const float*)d_in[5];
  const float* bq   = (const float*)d_in[6];
  const float* Wt1  = (const float*)d_in[7];
  // d_in[8] = b_t1: per-(b,g) constant shift -> softmax-invariant, unused
  const float* Wt2  = (const float*)d_in[9];
  const float* bt2  = (const float*)d_in[10];
  const float* Wout = (const float*)d_in[11];
  const float* bout = (const float*)d_in[12];
  float* out = (float*)d_out;

  float* ws      = (float*)d_ws;     // w1: 65536 floats; partial: 1024*PPAD floats (~9.7 MB)
  float* w1      = ws;
  float* partial = ws + TB * THEADS * TDIM;

  hipLaunchKernelGGL(tmca_prep, dim3(TB), dim3(256), 0, stream, ct, Wq, bq, Wkv, Wt1, w1);
  hipLaunchKernelGGL(tmca_main, dim3(BLK_PER_B, TB), dim3(256), 0, stream, X, msk, w1, partial);
  hipLaunchKernelGGL(tmca_fin, dim3(TB), dim3(256), 0, stream, partial, Wkv, bkv, Wt2, bt2,
                     Wout, bout, out);
}